// Round 8
// baseline (76.245 us; speedup 1.0000x reference)
//
#include <hip/hip_runtime.h>

// RepulsionLoss: points [B=4, N=8192, 3] fp32 -> scalar.
// Round 16:
//   R15 post-mortem: total 76.2us = ~40us harness workspace-poison fill
//   (untouchable, runs at 84% HBM peak) + ~36us build+query+gaps. The old
//   "constant 58us overhead" was this fill + extra dispatch gaps. Query is
//   now <40us (off top-5). Remaining lever per the trip-count model
//   (query time = per-wave serialized LDS trips / wave-overlap):
//   (a) 1024-thread query blocks (128 pts x 8 lanes) -> 16 waves/CU =
//       4 waves/SIMD (was 2), still 1 block/CU at 77KB LDS. VGPR cap 128,
//       R15 used 52 -> safe.
//   (b) stride-8 candidate splits, all lanes in the SAME loop instance
//       (R14 lesson): ring-0/1 serial trips ~31 -> ~18; ring-2 trips halve.
//   Build kernel unchanged (4 blocks, ~10us).

#define B_    4
#define N_    8192
#define KNN_  8
#define G_    12
#define C_    (G_ * G_ * G_)   // 1728
#define CS_   (C_ + 1)
#define PLANE_ (G_ * G_)       // 144
#define SLAB_CAP 4608          // float4 slots: 6 planes avg 4096, 11-sigma cap
#define CS_CAP   (6 * PLANE_ + 1)  // 865
#define QTHREADS_ 1024
#define BTHREADS_ 1024
#define NL_   8                // lanes per point

constexpr float GF_     = (float)G_;
constexpr float CELL_   = 1.0f / GF_;
constexpr float RADIUS_ = 0.07f;
constexpr float INV_H2_ = 1.0f / (0.03f * 0.03f);
constexpr float SCALE_  = 0.1f / (float)(B_ * N_ * KNN_);   // ALPHA / (B*N*K)

__device__ __forceinline__ int cell_coord(float x) {
    int c = (int)(x * GF_);
    return min(max(c, 0), G_ - 1);
}

__device__ __forceinline__ void insert8(float (&t)[KNN_], float v) {
#pragma unroll
    for (int k = 0; k < KNN_; k++) {
        const float lo = fminf(t[k], v);
        v = fmaxf(t[k], v);
        t[k] = lo;
    }
}

// One bitonic merge stage across lane pairs (xor dist): both lanes end with
// the sorted min-8 of the union of their two sorted lists. Valid for disjoint
// candidate multisets. xor 1/2/4 stays within a point's 8-lane group.
__device__ __forceinline__ void merge_pair(float (&t)[KNN_], const int dist) {
    float u[KNN_];
#pragma unroll
    for (int i2 = 0; i2 < KNN_; i2++)
        u[i2] = fminf(t[i2], __shfl_xor(t[KNN_ - 1 - i2], dist));
#pragma unroll
    for (int d = 4; d >= 1; d >>= 1) {
#pragma unroll
        for (int i2 = 0; i2 < KNN_; i2++) {
            if ((i2 & d) == 0) {
                const float a = u[i2], e = u[i2 + d];
                u[i2] = fminf(a, e); u[i2 + d] = fmaxf(a, e);
            }
        }
    }
#pragma unroll
    for (int i2 = 0; i2 < KNN_; i2++) t[i2] = u[i2];
}

// Candidate-split span scan from the LDS slab (slab-local indices), 8-way.
// All lanes in the SAME loop instance -> true SIMT parallel split.
__device__ __forceinline__ void scan_lds(const float4 (&sl)[SLAB_CAP],
                                         int j0, int j1, int l,
                                         float px, float py, float pz,
                                         float (&t)[KNN_]) {
    for (int j = j0 + l; j < j1; j += NL_) {
        const float4 Q = sl[j];
        const float dx = px - Q.x, dy = py - Q.y, dz = pz - Q.z;
        const float d2 = dx * dx + dy * dy + dz * dz;
        if (d2 < t[KNN_ - 1]) insert8(t, d2);
    }
}

// Span scan from global memory (ring >=3 only, essentially never).
__device__ __forceinline__ void scan_glb(const float4* __restrict__ sp,
                                         int j0, int j1, int l,
                                         float px, float py, float pz,
                                         float (&t)[KNN_]) {
    for (int j = j0 + l; j < j1; j += NL_) {
        const float4 Q = sp[j];
        const float dx = px - Q.x, dy = py - Q.y, dz = pz - Q.z;
        const float d2 = dx * dx + dy * dy + dz * dz;
        if (d2 < t[KNN_ - 1]) insert8(t, d2);
    }
}

// ---- fused build: 4 blocks (one per batch) x 1024 threads ----
// LDS histogram -> 256-thread shfl scan -> LDS-cursor scatter. Points
// stashed in registers between phases (static indexing).
__global__ __launch_bounds__(BTHREADS_) void build_kernel(
    const float* __restrict__ pts,
    int* __restrict__ cellStart,
    float4* __restrict__ sorted4,
    float* __restrict__ out)
{
    __shared__ int lcnt[C_];
    __shared__ int lcur[C_];
    __shared__ int wsum[4];

    const int b = blockIdx.x, tid = threadIdx.x;
    if (b == 0 && tid == 0) out[0] = 0.0f;          // out re-poisoned each replay
    for (int k = tid; k < C_; k += BTHREADS_) lcnt[k] = 0;
    __syncthreads();

    float fx[8], fy[8], fz[8]; int id[8];
#pragma unroll
    for (int k = 0; k < 8; k++) {
        const int g = b * N_ + k * BTHREADS_ + tid;
        fx[k] = pts[g * 3 + 0]; fy[k] = pts[g * 3 + 1]; fz[k] = pts[g * 3 + 2];
        id[k] = (cell_coord(fz[k]) * G_ + cell_coord(fy[k])) * G_ + cell_coord(fx[k]);
        atomicAdd(&lcnt[id[k]], 1);
    }
    __syncthreads();

    // scan: tid<256, 7 cells each (256*7=1792>=1728); barriers outside guards.
    const int lane = tid & 63, w = tid >> 6;
    int vals[7], tot = 0, incl = 0;
    const int c0 = tid * 7;
    if (tid < 256) {
#pragma unroll
        for (int k = 0; k < 7; k++) {
            const int c = c0 + k;
            const int v = (c < C_) ? lcnt[c] : 0;
            vals[k] = v; tot += v;
        }
        incl = tot;
#pragma unroll
        for (int off = 1; off < 64; off <<= 1) {
            const int v = __shfl_up(incl, off, 64);
            if (lane >= off) incl += v;
        }
        if (lane == 63) wsum[w] = incl;
    }
    __syncthreads();
    if (tid < 256) {
        int woff = 0;
        for (int ww = 0; ww < w; ww++) woff += wsum[ww];
        int run = woff + incl - tot;                 // exclusive base
#pragma unroll
        for (int k = 0; k < 7; k++) {
            const int c = c0 + k;
            if (c < C_) {
                cellStart[b * CS_ + c] = run;
                lcur[c] = run;
                run += vals[k];
            }
        }
        if (tid == 255) cellStart[b * CS_ + C_] = N_;
    }
    __syncthreads();

    // scatter from stashed registers via LDS cursors
#pragma unroll
    for (int k = 0; k < 8; k++) {
        const int pos = atomicAdd(&lcur[id[k]], 1);
        sorted4[(size_t)b * N_ + pos] = make_float4(fx[k], fy[k], fz[k], 0.0f);
    }
}

// ---- query: 256 blocks x 1024 threads, 128 sorted points/block, 8 lanes/pt ----
// 16 waves/CU = 4 waves/SIMD; 1 block/CU (77KB LDS); VGPR cap 128.
__global__ __launch_bounds__(QTHREADS_) void query_kernel(
    const float4* __restrict__ sorted4,
    const int* __restrict__ cellStart,
    float* __restrict__ out)
{
    __shared__ float4 slab[SLAB_CAP];
    __shared__ int    scs[CS_CAP];
    __shared__ float  bsum[16];

    const int tid  = threadIdx.x;
    const int b    = blockIdx.x >> 6;                  // 64 blocks/batch
    const int base = (blockIdx.x & 63) << 7;           // first point of block
    const int i    = base + (tid >> 3);                // this thread's point
    const int l    = tid & 7;                          // lane within point

    const int*    csg = cellStart + b * CS_;
    const float4* sp  = sorted4 + (size_t)b * N_;

    // Slab: block's points are cell-sorted; all ring<=2 reach lies in
    // z-planes [zf-2, zl+2] (<=6 planes; SLAB_CAP is ~11 sigma).
    const int zf  = cell_coord(sp[base].z);
    const int zl  = cell_coord(sp[base + 127].z);
    const int zlo = max(zf - 2, 0), zhi = min(zl + 2, G_ - 1);
    const int cs0 = zlo * PLANE_;
    const int cs1 = (zhi + 1) * PLANE_;                // <= C_
    const int start = csg[cs0];
    const int cnt   = csg[cs1] - start;
    const int csn   = cs1 - cs0 + 1;
    for (int k = tid; k < csn; k += QTHREADS_) scs[k]  = csg[cs0 + k];
    for (int k = tid; k < cnt; k += QTHREADS_) slab[k] = sp[start + k];
    __syncthreads();

    const float4 P = slab[i - start];
    const float px = P.x, py = P.y, pz = P.z;
    const int cx = cell_coord(px), cy = cell_coord(py), cz = cell_coord(pz);

    // Rings 0+1: 9 raster-contiguous x-rows, bounds from LDS cellStart slice.
    const int xa = max(cx - 1, 0), xb = min(cx + 1, G_ - 1);
    int j0[9], j1[9];
#pragma unroll
    for (int n = 0; n < 9; n++) {
        const int dz = n / 3 - 1, dy = n % 3 - 1;
        const int z = cz + dz, y = cy + dy;
        if ((unsigned)z < G_ && (unsigned)y < G_) {
            const int rb = (z * G_ + y) * G_ - cs0;
            j0[n] = scs[rb + xa] - start;
            j1[n] = scs[rb + xb + 1] - start;
        } else { j0[n] = 0; j1[n] = 0; }
    }

    float t[KNN_];
#pragma unroll
    for (int k = 0; k < KNN_; k++) t[k] = 1e30f;

#pragma unroll
    for (int n = 0; n < 9; n++)
        scan_lds(slab, j0[n], j1[n], l, px, py, pz, t);

    // True merged 8th-NN bound over the 8 lanes via temp copy.
    float m;
    {
        float tmp[KNN_];
#pragma unroll
        for (int k = 0; k < KNN_; k++) tmp[k] = t[k];
        merge_pair(tmp, 1); merge_pair(tmp, 2); merge_pair(tmp, 4);
        m = tmp[KNN_ - 1];
    }

    // Ring 2 (LDS, trimmed): for each row (z,y), az/ay = exact min distance
    // from the point to that cell slab; skip row if az^2+ay^2 >= m, else clip
    // the x-range to cells intersecting [px-w, px+w], w = sqrt(m-az^2-ay^2).
    // Any skipped candidate has d^2 >= m -> exact. Inner rows (|dz|<=1 and
    // |dy|<=1) contribute only their x = cx+-2 ring cells.
    if (CELL_ * CELL_ < m) {
        for (int dz = -2; dz <= 2; ++dz) {
            const int z = cz + dz; if ((unsigned)z >= G_) continue;
            const float azv = fmaxf(fmaxf(z * CELL_ - pz, pz - (z + 1) * CELL_), 0.0f);
            for (int dy = -2; dy <= 2; ++dy) {
                const int y = cy + dy; if ((unsigned)y >= G_) continue;
                const float ayv = fmaxf(fmaxf(y * CELL_ - py, py - (y + 1) * CELL_), 0.0f);
                const float rem = m - azv * azv - ayv * ayv;
                if (rem <= 0.0f) continue;
                const float wr = sqrtf(rem);
                const int xl = max(cell_coord(px - wr), cx - 2);
                const int xr = min(cell_coord(px + wr), cx + 2);
                const int rb = (z * G_ + y) * G_ - cs0;
                const bool innerzy = (dz >= -1) & (dz <= 1) & (dy >= -1) & (dy <= 1);
                if (!innerzy) {
                    if (xl <= xr)
                        scan_lds(slab, scs[rb + xl] - start, scs[rb + xr + 1] - start,
                                 l, px, py, pz, t);
                } else {
                    if (xl <= cx - 2)   // implies cx-2 >= 0 (xl >= 0)
                        scan_lds(slab, scs[rb + cx - 2] - start, scs[rb + cx - 1] - start,
                                 l, px, py, pz, t);
                    if (xr >= cx + 2)   // implies cx+2 <= 11 (xr <= 11)
                        scan_lds(slab, scs[rb + cx + 2] - start, scs[rb + cx + 3] - start,
                                 l, px, py, pz, t);
                }
            }
        }
        float e = t[KNN_ - 1];
        e = fminf(e, __shfl_xor(e, 1));
        e = fminf(e, __shfl_xor(e, 2));
        e = fminf(e, __shfl_xor(e, 4));
        m = fminf(m, e);
    }

    // Ring >=3 (global, essentially never): exact fallback.
    for (int r = 3; r < G_; r++) {
        const float dmin = (float)(r - 1) * CELL_;
        if (dmin * dmin >= m) break;
        for (int dz = -r; dz <= r; ++dz) {
            const int z = cz + dz; if ((unsigned)z >= G_) continue;
            const bool zface = (dz == -r) | (dz == r);
            for (int dy = -r; dy <= r; ++dy) {
                const int y = cy + dy; if ((unsigned)y >= G_) continue;
                const int rb = (z * G_ + y) * G_;
                if (zface | (dy == -r) | (dy == r)) {
                    const int x0 = max(cx - r, 0), x1 = min(cx + r, G_ - 1);
                    scan_glb(sp, csg[rb + x0], csg[rb + x1 + 1], l, px, py, pz, t);
                } else {
                    const int xm = cx - r, xp = cx + r;
                    if (xm >= 0) scan_glb(sp, csg[rb + xm], csg[rb + xm + 1], l, px, py, pz, t);
                    if (xp < G_) scan_glb(sp, csg[rb + xp], csg[rb + xp + 1], l, px, py, pz, t);
                }
            }
        }
        float e = t[KNN_ - 1];
        e = fminf(e, __shfl_xor(e, 1));
        e = fminf(e, __shfl_xor(e, 2));
        e = fminf(e, __shfl_xor(e, 4));
        m = fminf(m, e);
    }

    // Final exact top-8 of the 8 disjoint lane lists.
    merge_pair(t, 1); merge_pair(t, 2); merge_pair(t, 4);

    float tsum = 0.0f;
    if (l == 0) {
#pragma unroll
        for (int k = 0; k < KNN_; k++) {
            const float dm = fmaxf(t[k], 1e-12f);   // self: d2=0 -> dn=1e-6
            const float dn = sqrtf(dm);
            tsum += (RADIUS_ - dn) * __expf(-dm * INV_H2_);
        }
    }
#pragma unroll
    for (int off = 1; off < 64; off <<= 1) tsum += __shfl_xor(tsum, off);
    if ((tid & 63) == 0) bsum[tid >> 6] = tsum;
    __syncthreads();
    if (tid == 0) {
        float s = 0.0f;
#pragma unroll
        for (int w = 0; w < 16; w++) s += bsum[w];
        atomicAdd(out, s * SCALE_);
    }
}

extern "C" void kernel_launch(void* const* d_in, const int* in_sizes, int n_in,
                              void* d_out, int out_size, void* d_ws, size_t ws_size,
                              hipStream_t stream) {
    const float* pts = (const float*)d_in[0];
    float*       out = (float*)d_out;

    char* ws = (char*)d_ws;
    float4* sorted4   = (float4*)(ws);                            // 524288 B
    int*    cellStart = (int*)(ws + 524288);                      //  27664 B

    build_kernel<<<B_,            BTHREADS_, 0, stream>>>(pts, cellStart, sorted4, out);
    query_kernel<<<B_ * N_ / 128, QTHREADS_, 0, stream>>>(sorted4, cellStart, out);
}